// Round 3
// baseline (550.283 us; speedup 1.0000x reference)
//
#include <hip/hip_runtime.h>

// Problem constants
#define BB 4
#define LL 4096
#define DD 768
#define TD 2304          // 3*D
#define NFFT 8192
#define PI2 6.283185307179586f

__device__ __forceinline__ unsigned short f2b(float f) {
    unsigned u = __float_as_uint(f);
    unsigned r = (u + 0x7fffu + ((u >> 16) & 1u)) >> 16;
    return (unsigned short)r;
}
__device__ __forceinline__ float b2f(unsigned short h) {
    return __uint_as_float((unsigned)h << 16);
}
// packed fp32x2 -> bf16x2 (RNE), one VALU op
__device__ __forceinline__ unsigned cvt_pk_bf16(float lo, float hi) {
    unsigned r;
    asm("v_cvt_pk_bf16_f32 %0, %1, %2" : "=v"(r) : "v"(lo), "v"(hi));
    return r;
}

typedef __bf16 bf16x8 __attribute__((ext_vector_type(8)));
typedef float  f32x4  __attribute__((ext_vector_type(4)));

// ---------------------------------------------------------------------------
// Register FFT machinery (unchanged).
// ---------------------------------------------------------------------------
constexpr float TWC[16] = {
    1.f, 0.98078528f, 0.92387953f, 0.83146961f,
    0.70710678f, 0.55557023f, 0.38268343f, 0.19509032f,
    0.f, -0.19509032f, -0.38268343f, -0.55557023f,
    -0.70710678f, -0.83146961f, -0.92387953f, -0.98078528f};
constexpr float TWS[16] = {
    0.f, 0.19509032f, 0.38268343f, 0.55557023f,
    0.70710678f, 0.83146961f, 0.92387953f, 0.98078528f,
    1.f, 0.98078528f, 0.92387953f, 0.83146961f,
    0.70710678f, 0.55557023f, 0.38268343f, 0.19509032f};

template<int LOGN, bool INV>
__device__ __forceinline__ void reg_fft(float2* R) {
    constexpr int N = 1 << LOGN;
#pragma unroll
    for (int i = 0; i < N; ++i) {
        int j = 0;
#pragma unroll
        for (int b = 0; b < LOGN; ++b) if (i & (1 << b)) j |= (1 << (LOGN - 1 - b));
        if (j > i) { float2 tt = R[i]; R[i] = R[j]; R[j] = tt; }
    }
#pragma unroll
    for (int s = 1; s <= LOGN; ++s) {
        const int hm = 1 << (s - 1);
        const int tsh = 5 - s;
#pragma unroll
        for (int g = 0; g < N; g += (hm << 1)) {
#pragma unroll
            for (int j2 = 0; j2 < hm; ++j2) {
                const float wr = TWC[j2 << tsh];
                const float wi = INV ? TWS[j2 << tsh] : -TWS[j2 << tsh];
                float2 u = R[g + j2];
                float2 v = R[g + j2 + hm];
                float vr = v.x * wr - v.y * wi;
                float vi = v.x * wi + v.y * wr;
                R[g + j2]      = make_float2(u.x + vr, u.y + vi);
                R[g + j2 + hm] = make_float2(u.x - vr, u.y - vi);
            }
        }
    }
}

template<int NN>
__device__ __forceinline__ void ramp_mul(float2* R, float ang) {
    float s0, c0; __sincosf(ang, &s0, &c0);
    float wr = c0, wi = s0;
#pragma unroll
    for (int k = 1; k < NN; ++k) {
        float xr = R[k].x, xi = R[k].y;
        R[k] = make_float2(xr * wr - xi * wi, xr * wi + xi * wr);
        float nr = wr * c0 - wi * s0;
        float ni = wr * s0 + wi * c0;
        wr = nr; wi = ni;
    }
}

#define A1(t, k2) ((k2) * 288 + (t) + ((t) >> 3))
#define A2(k2, p, r) ((k2) * 272 + (r) * 17 + (p))
#define FFT_LDS 9216

__device__ __forceinline__ void eng_fwd(float2* buf, float2* R, int t) {
    reg_fft<5, false>(R);
    ramp_mul<32>(R, -PI2 * (float)t / 8192.0f);
    __syncthreads();
#pragma unroll
    for (int k2 = 0; k2 < 32; ++k2) buf[A1(t, k2)] = R[k2];
    __syncthreads();
    const int p = t & 15, c2 = (t >> 4) << 1;
#pragma unroll
    for (int q = 0; q < 16; ++q) {
        R[q]      = buf[A1(p + 16 * q, c2)];
        R[16 + q] = buf[A1(p + 16 * q, c2 + 1)];
    }
    reg_fft<4, false>(R);
    reg_fft<4, false>(R + 16);
    float a2 = -PI2 * (float)p / 256.0f;
    ramp_mul<16>(R, a2);
    ramp_mul<16>(R + 16, a2);
    __syncthreads();
#pragma unroll
    for (int r = 0; r < 16; ++r) {
        buf[A2(c2, p, r)]     = R[r];
        buf[A2(c2 + 1, p, r)] = R[16 + r];
    }
    __syncthreads();
    const int rr = p;
#pragma unroll
    for (int pp = 0; pp < 16; ++pp) {
        R[pp]      = buf[A2(c2, pp, rr)];
        R[16 + pp] = buf[A2(c2 + 1, pp, rr)];
    }
    reg_fft<4, false>(R);
    reg_fft<4, false>(R + 16);
}

__device__ __forceinline__ void eng_inv(float2* buf, float2* R, int t) {
    const int p = t & 15, c2 = (t >> 4) << 1, rr = p;
    reg_fft<4, true>(R);
    reg_fft<4, true>(R + 16);
    __syncthreads();
#pragma unroll
    for (int pp = 0; pp < 16; ++pp) {
        buf[A2(c2, pp, rr)]     = R[pp];
        buf[A2(c2 + 1, pp, rr)] = R[16 + pp];
    }
    __syncthreads();
#pragma unroll
    for (int r = 0; r < 16; ++r) {
        R[r]      = buf[A2(c2, p, r)];
        R[16 + r] = buf[A2(c2 + 1, p, r)];
    }
    float a2 = PI2 * (float)p / 256.0f;
    ramp_mul<16>(R, a2);
    ramp_mul<16>(R + 16, a2);
    reg_fft<4, true>(R);
    reg_fft<4, true>(R + 16);
    __syncthreads();
#pragma unroll
    for (int q = 0; q < 16; ++q) {
        buf[A1(p + 16 * q, c2)]     = R[q];
        buf[A1(p + 16 * q, c2 + 1)] = R[16 + q];
    }
    __syncthreads();
#pragma unroll
    for (int k2 = 0; k2 < 32; ++k2) R[k2] = buf[A1(t, k2)];
    ramp_mul<32>(R, PI2 * (float)t / 8192.0f);
    reg_fft<5, true>(R);
}

// ---------------------------------------------------------------------------
// K0: fp32 -> bf16 cast (two sources fused), float4 granularity
// ---------------------------------------------------------------------------
__global__ __launch_bounds__(256) void k_cast_pair(
        const float* __restrict__ srcA, unsigned long long nA4,
        const float* __restrict__ srcB, unsigned long long nB4,
        unsigned short* __restrict__ dstA, unsigned short* __restrict__ dstB) {
    unsigned long long i = (unsigned long long)blockIdx.x * 256 + threadIdx.x;
    const float* s; unsigned short* d;
    if (i < nA4)            { s = srcA + i * 4;         d = dstA + i * 4; }
    else if (i < nA4 + nB4) { unsigned long long j = i - nA4; s = srcB + j * 4; d = dstB + j * 4; }
    else return;
    float4 v = *(const float4*)s;
    unsigned long long p = (unsigned long long)f2b(v.x)
                         | ((unsigned long long)f2b(v.y) << 16)
                         | ((unsigned long long)f2b(v.z) << 32)
                         | ((unsigned long long)f2b(v.w) << 48);
    *(unsigned long long*)d = p;
}

// ---------------------------------------------------------------------------
// GEMM core (NT, bf16 MFMA): BK=64, XOR-swizzled 16B slots, XCD-aware block
// swizzle. UNCHANGED (known-good).
// ---------------------------------------------------------------------------
#define GEMM_CORE                                                               \
    __shared__ unsigned char AsB[16384];                                        \
    __shared__ unsigned char BsB[16384];                                        \
    const int tid  = threadIdx.x;                                               \
    const int lane = tid & 63;                                                  \
    const int w    = tid >> 6;                                                  \
    const int wr   = w >> 1, wc = w & 1;                                        \
    const int nbx  = (int)gridDim.x;                                            \
    int bid = (int)blockIdx.y * nbx + (int)blockIdx.x;                          \
    { const int cpx = (nbx * (int)gridDim.y) >> 3;                              \
      bid = (bid & 7) * cpx + (bid >> 3); }                                     \
    const int m0 = (bid / nbx) * 128, n0 = (bid % nbx) * 128;                   \
    f32x4 acc[4][4] = {};                                                       \
    const int srow = lane >> 3;          /* 0..7 within 8-row chunk */          \
    const int sslot = (lane & 7) ^ srow; /* swizzled global 16B slot */         \
    for (int k0 = 0; k0 < K; k0 += 64) {                                        \
        _Pragma("unroll")                                                       \
        for (int c = 0; c < 4; ++c) {                                           \
            int chunk = w * 4 + c;                                              \
            int row = chunk * 8 + srow;                                         \
            const char* ga = (const char*)A  + (((size_t)(m0 + row) * K + k0) * 2) + sslot * 16; \
            __builtin_amdgcn_global_load_lds(                                   \
                (const __attribute__((address_space(1))) void*)ga,              \
                (__attribute__((address_space(3))) void*)(AsB + chunk * 1024), 16, 0, 0); \
            const char* gb = (const char*)Bw + (((size_t)(n0 + row) * K + k0) * 2) + sslot * 16; \
            __builtin_amdgcn_global_load_lds(                                   \
                (const __attribute__((address_space(1))) void*)gb,              \
                (__attribute__((address_space(3))) void*)(BsB + chunk * 1024), 16, 0, 0); \
        }                                                                       \
        __syncthreads();                                                        \
        const int quad = lane >> 4;                                             \
        const int rsel = lane & 15;                                             \
        _Pragma("unroll")                                                       \
        for (int kk = 0; kk < 2; ++kk) {                                        \
            bf16x8 af[4], bfr[4];                                               \
            _Pragma("unroll")                                                   \
            for (int i = 0; i < 4; ++i) {                                       \
                int rowA = wr * 64 + i * 16 + rsel;                             \
                int slotA = (kk * 4 + quad) ^ (rsel & 7);                       \
                af[i]  = *(const bf16x8*)(AsB + rowA * 128 + slotA * 16);       \
                int rowB = wc * 64 + i * 16 + rsel;                             \
                bfr[i] = *(const bf16x8*)(BsB + rowB * 128 + slotA * 16);       \
            }                                                                   \
            _Pragma("unroll")                                                   \
            for (int i = 0; i < 4; ++i)                                         \
                _Pragma("unroll")                                               \
                for (int j = 0; j < 4; ++j)                                     \
                    acc[i][j] = __builtin_amdgcn_mfma_f32_16x16x32_bf16(af[i], bfr[j], acc[i][j], 0, 0, 0); \
        }                                                                       \
        __syncthreads();                                                        \
    }

// K1: GEMM1 with TRANSPOSED epilogue: x written as (B, 3D, L) bf16.
__global__ __launch_bounds__(256) void k_gemm1_xt(
        const unsigned short* __restrict__ A, const unsigned short* __restrict__ Bw,
        const float* __restrict__ bias, unsigned short* __restrict__ xT,
        int K) {
    GEMM_CORE
    const int cq = lane >> 4;
    const int cn = lane & 15;
    const int b  = m0 >> 12;                         // m0 / LL (tile never spans b)
    const int lb = (m0 & 4095) + wr * 64 + cq * 4;   // l base for this lane
#pragma unroll
    for (int j = 0; j < 4; ++j) {
        int col = n0 + wc * 64 + j * 16 + cn;        // channel in [0, 3D)
        float bv = bias[col];
        unsigned short* cp = xT + ((size_t)b * TD + col) * LL + lb;
#pragma unroll
        for (int i = 0; i < 4; ++i) {
            uint2 p;
            p.x = cvt_pk_bf16(acc[i][j][0] + bv, acc[i][j][1] + bv);
            p.y = cvt_pk_bf16(acc[i][j][2] + bv, acc[i][j][3] + bv);
            *(uint2*)(cp + i * 16) = p;
        }
    }
}

// K6: GEMM2, fp32 row-major output (final result layout is fixed).
__global__ __launch_bounds__(256) void k_gemm_mfma(
        const unsigned short* __restrict__ A, const unsigned short* __restrict__ Bw,
        const float* __restrict__ bias, float* __restrict__ C,
        int N, int K) {
    GEMM_CORE
    const int cq = lane >> 4;
    const int cn = lane & 15;
#pragma unroll
    for (int j = 0; j < 4; ++j) {
        int col = n0 + wc * 64 + j * 16 + cn;
        float bv = bias[col];
#pragma unroll
        for (int i = 0; i < 4; ++i) {
            int rbase = m0 + wr * 64 + i * 16 + cq * 4;
#pragma unroll
            for (int r = 0; r < 4; ++r)
                C[(size_t)(rbase + r) * N + col] = acc[i][j][r] + bv;
        }
    }
}

// ---------------------------------------------------------------------------
// ld_row18: load x[l0-2 .. l0+15] (bf16) from a channel row into fp32 regs.
// ---------------------------------------------------------------------------
__device__ __forceinline__ void ld_row18(const unsigned short* __restrict__ r,
                                         int l0, float* a) {
    unsigned ql = 0;
    if (l0 >= 2) ql = *(const unsigned*)(r + l0 - 2);
    a[0] = b2f((unsigned short)(ql & 0xffffu));
    a[1] = b2f((unsigned short)(ql >> 16));
    uint4 q0 = *(const uint4*)(r + l0);
    uint4 q1 = *(const uint4*)(r + l0 + 8);
    unsigned qq[8] = {q0.x, q0.y, q0.z, q0.w, q1.x, q1.y, q1.z, q1.w};
#pragma unroll
    for (int k2 = 0; k2 < 8; ++k2) {
        a[2 + 2 * k2] = b2f((unsigned short)(qq[k2] & 0xffffu));
        a[3 + 2 * k2] = b2f((unsigned short)(qq[k2] >> 16));
    }
}

// ---------------------------------------------------------------------------
// K2+K4 FUSED: depthwise short conv (k=3, causal) + pre-gate + register-FFT
// long conv + post-gate. One block per channel d; both batch-pairs processed
// sequentially with the kernel spectrum kf held in registers (read once).
// Conv computed in registers from xT (B,3D,L); redistributed to the strided
// FFT ownership pattern through the (idle) FFT LDS buffer. x2 gate carried
// as 16 packed bf16x2 registers through the FFT. v enters the FFT at fp32.
// ---------------------------------------------------------------------------
__global__ __launch_bounds__(256) void k_convfft(
        const unsigned short* __restrict__ xT,
        const float* __restrict__ conv_w, const float* __restrict__ conv_b,
        const float2* __restrict__ kf,
        unsigned short* __restrict__ yg) {
    __shared__ float2 buf[FFT_LDS];
    const int d = blockIdx.x;
    const int t = threadIdx.x;
    const int l0 = t << 4;
    const float w10 = conv_w[3*d],          w11 = conv_w[3*d+1],          w12 = conv_w[3*d+2];
    const float w20 = conv_w[3*(DD+d)],     w21 = conv_w[3*(DD+d)+1],     w22 = conv_w[3*(DD+d)+2];
    const float w30 = conv_w[3*(2*DD+d)],   w31 = conv_w[3*(2*DD+d)+1],   w32 = conv_w[3*(2*DD+d)+2];
    const float c1 = conv_b[d], c2 = conv_b[DD + d], c3 = conv_b[2*DD + d];
    const float2* kd = kf + (size_t)d * NFFT;
    float2 w[32];                                  // kernel spectrum (pair 0 load)
    float2*   vstage = buf;                        // [4096] float2 (v pairs, fp32)
    unsigned* xstage = (unsigned*)(buf + 4096);    // [4096] packed bf16 x2 pairs

#pragma unroll 1
    for (int pair = 0; pair < 2; ++pair) {
        const int b0 = pair * 2, b1 = b0 + 1;
        // --- conv compute + stage ---
        {
            float a[18], q1[16], vv0[16], vv1[16];
            ld_row18(xT + ((size_t)b0 * TD + d) * LL, l0, a);
#pragma unroll
            for (int k = 0; k < 16; ++k) q1[k] = w10*a[k] + w11*a[k+1] + w12*a[k+2] + c1;
            ld_row18(xT + ((size_t)b0 * TD + 2*DD + d) * LL, l0, a);
#pragma unroll
            for (int k = 0; k < 16; ++k) vv0[k] = (w30*a[k] + w31*a[k+1] + w32*a[k+2] + c3) * q1[k];
            ld_row18(xT + ((size_t)b1 * TD + d) * LL, l0, a);
#pragma unroll
            for (int k = 0; k < 16; ++k) q1[k] = w10*a[k] + w11*a[k+1] + w12*a[k+2] + c1;
            ld_row18(xT + ((size_t)b1 * TD + 2*DD + d) * LL, l0, a);
#pragma unroll
            for (int k = 0; k < 16; ++k) vv1[k] = (w30*a[k] + w31*a[k+1] + w32*a[k+2] + c3) * q1[k];
#pragma unroll
            for (int k = 0; k < 16; ++k) vstage[l0 + k] = make_float2(vv0[k], vv1[k]);
            ld_row18(xT + ((size_t)b0 * TD + DD + d) * LL, l0, a);
#pragma unroll
            for (int k = 0; k < 16; ++k) q1[k] = w20*a[k] + w21*a[k+1] + w22*a[k+2] + c2;
            ld_row18(xT + ((size_t)b1 * TD + DD + d) * LL, l0, a);
#pragma unroll
            for (int k = 0; k < 16; ++k)
                xstage[l0 + k] = cvt_pk_bf16(q1[k], w20*a[k] + w21*a[k+1] + w22*a[k+2] + c2);
        }
        __syncthreads();
        // --- redistribute to strided FFT ownership ---
        float2 R[32];
        unsigned x2p[16];
#pragma unroll
        for (int j = 0; j < 16; ++j) {
            int idx = t + 256 * j;
            R[j] = vstage[idx];
            x2p[j] = xstage[idx];
            R[16 + j] = make_float2(0.f, 0.f);
        }
        // (eng_fwd's internal pre-write __syncthreads protects the reads above)
        if (pair == 0) {
#pragma unroll
            for (int i = 0; i < 32; ++i) w[i] = kd[i * 256 + t];   // overlaps fwd FFT
        }
        eng_fwd(buf, R, t);
#pragma unroll
        for (int i = 0; i < 32; ++i) {
            float2 zv = R[i];
            R[i] = make_float2(zv.x * w[i].x - zv.y * w[i].y, zv.x * w[i].y + zv.y * w[i].x);
        }
        eng_inv(buf, R, t);
        unsigned short* o1 = yg + ((size_t)b0 * DD + d) * LL;
        unsigned short* o2 = o1 + (size_t)DD * LL;
#pragma unroll
        for (int j = 0; j < 16; ++j) {
            int idx = t + 256 * j;
            o1[idx] = f2b(R[j].x * b2f((unsigned short)(x2p[j] & 0xffffu)));
            o2[idx] = f2b(R[j].y * b2f((unsigned short)(x2p[j] >> 16)));
        }
        if (pair == 0) __syncthreads();   // eng_inv tail reads vs pair-1 staging writes
    }
}

// ---------------------------------------------------------------------------
// K3a: implicit filter MLP; output TRANSPOSED h3g[16][LL]
// ---------------------------------------------------------------------------
__global__ __launch_bounds__(256) void k_filter_mlp(
        const float* __restrict__ z,
        const float* __restrict__ fw1, const float* __restrict__ fb1,
        const float* __restrict__ fw2, const float* __restrict__ fb2,
        const float* __restrict__ fw3, const float* __restrict__ fb3,
        const float* __restrict__ freq, float* __restrict__ h3g) {
    int l = blockIdx.x * 256 + threadIdx.x;
    float z0 = z[l*3+0], z1 = z[l*3+1], z2 = z[l*3+2];
    float h1[16], h2[16];
#pragma unroll
    for (int j = 0; j < 16; ++j) {
        float a = z0*fw1[j*3+0] + z1*fw1[j*3+1] + z2*fw1[j*3+2] + fb1[j];
        h1[j] = sinf(freq[j] * a);
    }
#pragma unroll
    for (int j = 0; j < 16; ++j) {
        float a = fb2[j];
#pragma unroll
        for (int i = 0; i < 16; ++i) a += h1[i] * fw2[j*16+i];
        h2[j] = sinf(freq[j] * a);
    }
#pragma unroll
    for (int j = 0; j < 16; ++j) {
        float a = fb3[j];
#pragma unroll
        for (int i = 0; i < 16; ++i) a += h2[i] * fw3[j*16+i];
        h3g[j * LL + l] = sinf(freq[j] * a);
    }
}

// ---------------------------------------------------------------------------
// K3b: fused filter construction + forward FFT; kf in engine order, 1/N and
// filter_bias folded in.
// ---------------------------------------------------------------------------
__global__ __launch_bounds__(256) void k_filter_fft(
        const float* __restrict__ h3g, const float* __restrict__ fw4,
        const float* __restrict__ fbias, float2* __restrict__ kf) {
    __shared__ float2 buf[FFT_LDS];
    const int d = blockIdx.x, t = threadIdx.x;
    float w4[16];
#pragma unroll
    for (int i = 0; i < 16; ++i) w4[i] = fw4[d * 16 + i];
    const float min_d = 3.070113457325394f;
    const float max_d = 15.35056728662697f;
    const float ad = min_d + (max_d - min_d) * ((float)d / 767.0f);
    float2 R[32];
#pragma unroll
    for (int j = 0; j < 16; ++j) {
        int l = t + 256 * j;
        float acc = 0.f;
#pragma unroll
        for (int i = 0; i < 16; ++i) acc += h3g[i * LL + l] * w4[i];
        acc *= __expf(-((float)l / 4095.0f) * ad);
        R[j] = make_float2(acc, 0.f);
        R[16 + j] = make_float2(0.f, 0.f);
    }
    eng_fwd(buf, R, t);
    const float fb = fbias[d];
    const float inv_n = 1.0f / (float)NFFT;
    float2* kd = kf + (size_t)d * NFFT;
#pragma unroll
    for (int i = 0; i < 32; ++i)
        kd[i * 256 + t] = make_float2((R[i].x + fb) * inv_n, R[i].y * inv_n);
}

// ---------------------------------------------------------------------------
// K5: transpose: yg (B,D,L) bf16 -> ygT (B,L,D) bf16, 64x64 LDS tile
// ---------------------------------------------------------------------------
__global__ __launch_bounds__(256) void k_transpose_cast(
        const unsigned short* __restrict__ yg, unsigned short* __restrict__ ygT) {
    __shared__ float t[64][65];
    const int b = blockIdx.z;
    const int d0 = blockIdx.y * 64;
    const int l0 = blockIdx.x * 64;
    for (int idx = threadIdx.x; idx < 4096; idx += 256) {
        int r = idx >> 6, c = idx & 63;
        t[r][c] = b2f(yg[((size_t)(b * DD + d0 + r)) * LL + l0 + c]);
    }
    __syncthreads();
    for (int idx = threadIdx.x; idx < 2048; idx += 256) {
        int r = idx >> 5, c = (idx & 31) * 2;
        unsigned int p = (unsigned int)f2b(t[c][r]) | ((unsigned int)f2b(t[c+1][r]) << 16);
        *(unsigned int*)&ygT[((size_t)(b * LL + l0 + r)) * DD + d0 + c] = p;
    }
}

// ---------------------------------------------------------------------------
extern "C" void kernel_launch(void* const* d_in, const int* in_sizes, int n_in,
                              void* d_out, int out_size, void* d_ws, size_t ws_size,
                              hipStream_t stream) {
    const float* u      = (const float*)d_in[0];
    const float* w_in   = (const float*)d_in[1];
    const float* b_in   = (const float*)d_in[2];
    const float* w_out  = (const float*)d_in[3];
    const float* b_out  = (const float*)d_in[4];
    const float* conv_w = (const float*)d_in[5];
    const float* conv_b = (const float*)d_in[6];
    const float* z      = (const float*)d_in[7];
    const float* fw1    = (const float*)d_in[8];
    const float* fb1    = (const float*)d_in[9];
    const float* fw2    = (const float*)d_in[10];
    const float* fb2    = (const float*)d_in[11];
    const float* fw3    = (const float*)d_in[12];
    const float* fb3    = (const float*)d_in[13];
    const float* fw4    = (const float*)d_in[14];
    const float* freq   = (const float*)d_in[15];
    const float* fbias  = (const float*)d_in[16];

    // Workspace layout (xT and kf must now COEXIST — no aliasing):
    //   xT       @ 0          75,497,472  (B,3D,L bf16)
    //   kf       @ 75497472   50,331,648  (D x NFFT float2)
    //   h3g      @ 125829120     262,144
    //   w_out_bf @ 126091264   1,179,648
    //   yg       @ 127270912  25,165,824  (B,D,L bf16, gated y)
    //   ygT      @ 152436736  25,165,824
    //   u_bf     @ 177602560  25,165,824
    //   w_in_bf  @ 202768384   3,538,944   -> high water ~206.3 MB
    char* ws = (char*)d_ws;
    unsigned short* xT       = (unsigned short*)(ws);
    float2* kf               = (float2*)(ws + 75497472);
    float*  h3g              = (float*)(ws + 125829120);
    unsigned short* w_out_bf = (unsigned short*)(ws + 126091264);
    unsigned short* yg       = (unsigned short*)(ws + 127270912);
    unsigned short* ygT      = (unsigned short*)(ws + 152436736);
    unsigned short* u_bf     = (unsigned short*)(ws + 177602560);
    unsigned short* w_in_bf  = (unsigned short*)(ws + 202768384);

    // 0) cast u, w_in to bf16
    k_cast_pair<<<(3145728 + 442368 + 255) / 256, 256, 0, stream>>>(
        u, 3145728ULL, w_in, 442368ULL, u_bf, w_in_bf);
    // 1) x = u @ w_in^T + b_in  (bf16 MFMA), written TRANSPOSED as (B,3D,L)
    k_gemm1_xt<<<dim3(TD/128, (BB*LL)/128), 256, 0, stream>>>(u_bf, w_in_bf, b_in, xT, DD);
    // 2) filter: MLP -> fused (modulated k + FFT), engine-order spectrum
    k_filter_mlp<<<LL/256, 256, 0, stream>>>(z, fw1, fb1, fw2, fb2, fw3, fb3, freq, h3g);
    k_filter_fft<<<DD, 256, 0, stream>>>(h3g, fw4, fbias, kf);
    // 2b) cast w_out -> bf16
    k_cast_pair<<<(147456 + 255) / 256, 256, 0, stream>>>(
        w_out, 147456ULL, (const float*)0, 0ULL, w_out_bf, (unsigned short*)0);
    // 3) FUSED short conv + pre-gate + FFT long conv + post-gate
    k_convfft<<<DD, 256, 0, stream>>>(xT, conv_w, conv_b, kf, yg);
    // 4) transpose gated y -> (B,L,D) bf16
    k_transpose_cast<<<dim3(LL/64, DD/64, BB), 256, 0, stream>>>(yg, ygT);
    // 5) out = ygT @ w_out^T + b_out  (bf16 MFMA, fp32 out)
    k_gemm_mfma<<<dim3(DD/128, (BB*LL)/128), 256, 0, stream>>>(ygT, w_out_bf, b_out, (float*)d_out, DD, DD);
}

// Round 4
// 374.894 us; speedup vs baseline: 1.4678x; 1.4678x over previous
//
#include <hip/hip_runtime.h>

// Problem constants
#define BB 4
#define LL 4096
#define DD 768
#define TD 2304          // 3*D
#define NFFT 8192
#define PI2 6.283185307179586f

__device__ __forceinline__ unsigned short f2b(float f) {
    unsigned u = __float_as_uint(f);
    unsigned r = (u + 0x7fffu + ((u >> 16) & 1u)) >> 16;
    return (unsigned short)r;
}
__device__ __forceinline__ float b2f(unsigned short h) {
    return __uint_as_float((unsigned)h << 16);
}
// packed fp32x2 -> bf16x2 (RNE), one VALU op
__device__ __forceinline__ unsigned cvt_pk_bf16(float lo, float hi) {
    unsigned r;
    asm("v_cvt_pk_bf16_f32 %0, %1, %2" : "=v"(r) : "v"(lo), "v"(hi));
    return r;
}

typedef __bf16 bf16x8 __attribute__((ext_vector_type(8)));
typedef float  f32x4  __attribute__((ext_vector_type(4)));

// ---------------------------------------------------------------------------
// Register FFT machinery (unchanged).
// ---------------------------------------------------------------------------
constexpr float TWC[16] = {
    1.f, 0.98078528f, 0.92387953f, 0.83146961f,
    0.70710678f, 0.55557023f, 0.38268343f, 0.19509032f,
    0.f, -0.19509032f, -0.38268343f, -0.55557023f,
    -0.70710678f, -0.83146961f, -0.92387953f, -0.98078528f};
constexpr float TWS[16] = {
    0.f, 0.19509032f, 0.38268343f, 0.55557023f,
    0.70710678f, 0.83146961f, 0.92387953f, 0.98078528f,
    1.f, 0.98078528f, 0.92387953f, 0.83146961f,
    0.70710678f, 0.55557023f, 0.38268343f, 0.19509032f};

template<int LOGN, bool INV>
__device__ __forceinline__ void reg_fft(float2* R) {
    constexpr int N = 1 << LOGN;
#pragma unroll
    for (int i = 0; i < N; ++i) {
        int j = 0;
#pragma unroll
        for (int b = 0; b < LOGN; ++b) if (i & (1 << b)) j |= (1 << (LOGN - 1 - b));
        if (j > i) { float2 tt = R[i]; R[i] = R[j]; R[j] = tt; }
    }
#pragma unroll
    for (int s = 1; s <= LOGN; ++s) {
        const int hm = 1 << (s - 1);
        const int tsh = 5 - s;
#pragma unroll
        for (int g = 0; g < N; g += (hm << 1)) {
#pragma unroll
            for (int j2 = 0; j2 < hm; ++j2) {
                const float wr = TWC[j2 << tsh];
                const float wi = INV ? TWS[j2 << tsh] : -TWS[j2 << tsh];
                float2 u = R[g + j2];
                float2 v = R[g + j2 + hm];
                float vr = v.x * wr - v.y * wi;
                float vi = v.x * wi + v.y * wr;
                R[g + j2]      = make_float2(u.x + vr, u.y + vi);
                R[g + j2 + hm] = make_float2(u.x - vr, u.y - vi);
            }
        }
    }
}

template<int NN>
__device__ __forceinline__ void ramp_mul(float2* R, float ang) {
    float s0, c0; __sincosf(ang, &s0, &c0);
    float wr = c0, wi = s0;
#pragma unroll
    for (int k = 1; k < NN; ++k) {
        float xr = R[k].x, xi = R[k].y;
        R[k] = make_float2(xr * wr - xi * wi, xr * wi + xi * wr);
        float nr = wr * c0 - wi * s0;
        float ni = wr * s0 + wi * c0;
        wr = nr; wi = ni;
    }
}

#define A1(t, k2) ((k2) * 288 + (t) + ((t) >> 3))
#define A2(k2, p, r) ((k2) * 272 + (r) * 17 + (p))
#define FFT_LDS 9216

__device__ __forceinline__ void eng_fwd(float2* buf, float2* R, int t) {
    reg_fft<5, false>(R);
    ramp_mul<32>(R, -PI2 * (float)t / 8192.0f);
    __syncthreads();
#pragma unroll
    for (int k2 = 0; k2 < 32; ++k2) buf[A1(t, k2)] = R[k2];
    __syncthreads();
    const int p = t & 15, c2 = (t >> 4) << 1;
#pragma unroll
    for (int q = 0; q < 16; ++q) {
        R[q]      = buf[A1(p + 16 * q, c2)];
        R[16 + q] = buf[A1(p + 16 * q, c2 + 1)];
    }
    reg_fft<4, false>(R);
    reg_fft<4, false>(R + 16);
    float a2 = -PI2 * (float)p / 256.0f;
    ramp_mul<16>(R, a2);
    ramp_mul<16>(R + 16, a2);
    __syncthreads();
#pragma unroll
    for (int r = 0; r < 16; ++r) {
        buf[A2(c2, p, r)]     = R[r];
        buf[A2(c2 + 1, p, r)] = R[16 + r];
    }
    __syncthreads();
    const int rr = p;
#pragma unroll
    for (int pp = 0; pp < 16; ++pp) {
        R[pp]      = buf[A2(c2, pp, rr)];
        R[16 + pp] = buf[A2(c2 + 1, pp, rr)];
    }
    reg_fft<4, false>(R);
    reg_fft<4, false>(R + 16);
}

__device__ __forceinline__ void eng_inv(float2* buf, float2* R, int t) {
    const int p = t & 15, c2 = (t >> 4) << 1, rr = p;
    reg_fft<4, true>(R);
    reg_fft<4, true>(R + 16);
    __syncthreads();
#pragma unroll
    for (int pp = 0; pp < 16; ++pp) {
        buf[A2(c2, pp, rr)]     = R[pp];
        buf[A2(c2 + 1, pp, rr)] = R[16 + pp];
    }
    __syncthreads();
#pragma unroll
    for (int r = 0; r < 16; ++r) {
        R[r]      = buf[A2(c2, p, r)];
        R[16 + r] = buf[A2(c2 + 1, p, r)];
    }
    float a2 = PI2 * (float)p / 256.0f;
    ramp_mul<16>(R, a2);
    ramp_mul<16>(R + 16, a2);
    reg_fft<4, true>(R);
    reg_fft<4, true>(R + 16);
    __syncthreads();
#pragma unroll
    for (int q = 0; q < 16; ++q) {
        buf[A1(p + 16 * q, c2)]     = R[q];
        buf[A1(p + 16 * q, c2 + 1)] = R[16 + q];
    }
    __syncthreads();
#pragma unroll
    for (int k2 = 0; k2 < 32; ++k2) R[k2] = buf[A1(t, k2)];
    ramp_mul<32>(R, PI2 * (float)t / 8192.0f);
    reg_fft<5, true>(R);
}

// ---------------------------------------------------------------------------
// K0: fp32 -> bf16 cast (two sources fused), float4 granularity
// ---------------------------------------------------------------------------
__global__ __launch_bounds__(256) void k_cast_pair(
        const float* __restrict__ srcA, unsigned long long nA4,
        const float* __restrict__ srcB, unsigned long long nB4,
        unsigned short* __restrict__ dstA, unsigned short* __restrict__ dstB) {
    unsigned long long i = (unsigned long long)blockIdx.x * 256 + threadIdx.x;
    const float* s; unsigned short* d;
    if (i < nA4)            { s = srcA + i * 4;         d = dstA + i * 4; }
    else if (i < nA4 + nB4) { unsigned long long j = i - nA4; s = srcB + j * 4; d = dstB + j * 4; }
    else return;
    float4 v = *(const float4*)s;
    unsigned long long p = (unsigned long long)f2b(v.x)
                         | ((unsigned long long)f2b(v.y) << 16)
                         | ((unsigned long long)f2b(v.z) << 32)
                         | ((unsigned long long)f2b(v.w) << 48);
    *(unsigned long long*)d = p;
}

// ---------------------------------------------------------------------------
// GEMM core (NT, bf16 MFMA): BK=64, XOR-swizzled 16B slots, XCD-aware block
// swizzle. UNCHANGED (known-good).
// ---------------------------------------------------------------------------
#define GEMM_CORE                                                               \
    __shared__ unsigned char AsB[16384];                                        \
    __shared__ unsigned char BsB[16384];                                        \
    const int tid  = threadIdx.x;                                               \
    const int lane = tid & 63;                                                  \
    const int w    = tid >> 6;                                                  \
    const int wr   = w >> 1, wc = w & 1;                                        \
    const int nbx  = (int)gridDim.x;                                            \
    int bid = (int)blockIdx.y * nbx + (int)blockIdx.x;                          \
    { const int cpx = (nbx * (int)gridDim.y) >> 3;                              \
      bid = (bid & 7) * cpx + (bid >> 3); }                                     \
    const int m0 = (bid / nbx) * 128, n0 = (bid % nbx) * 128;                   \
    f32x4 acc[4][4] = {};                                                       \
    const int srow = lane >> 3;          /* 0..7 within 8-row chunk */          \
    const int sslot = (lane & 7) ^ srow; /* swizzled global 16B slot */         \
    for (int k0 = 0; k0 < K; k0 += 64) {                                        \
        _Pragma("unroll")                                                       \
        for (int c = 0; c < 4; ++c) {                                           \
            int chunk = w * 4 + c;                                              \
            int row = chunk * 8 + srow;                                         \
            const char* ga = (const char*)A  + (((size_t)(m0 + row) * K + k0) * 2) + sslot * 16; \
            __builtin_amdgcn_global_load_lds(                                   \
                (const __attribute__((address_space(1))) void*)ga,              \
                (__attribute__((address_space(3))) void*)(AsB + chunk * 1024), 16, 0, 0); \
            const char* gb = (const char*)Bw + (((size_t)(n0 + row) * K + k0) * 2) + sslot * 16; \
            __builtin_amdgcn_global_load_lds(                                   \
                (const __attribute__((address_space(1))) void*)gb,              \
                (__attribute__((address_space(3))) void*)(BsB + chunk * 1024), 16, 0, 0); \
        }                                                                       \
        __syncthreads();                                                        \
        const int quad = lane >> 4;                                             \
        const int rsel = lane & 15;                                             \
        _Pragma("unroll")                                                       \
        for (int kk = 0; kk < 2; ++kk) {                                        \
            bf16x8 af[4], bfr[4];                                               \
            _Pragma("unroll")                                                   \
            for (int i = 0; i < 4; ++i) {                                       \
                int rowA = wr * 64 + i * 16 + rsel;                             \
                int slotA = (kk * 4 + quad) ^ (rsel & 7);                       \
                af[i]  = *(const bf16x8*)(AsB + rowA * 128 + slotA * 16);       \
                int rowB = wc * 64 + i * 16 + rsel;                             \
                bfr[i] = *(const bf16x8*)(BsB + rowB * 128 + slotA * 16);       \
            }                                                                   \
            _Pragma("unroll")                                                   \
            for (int i = 0; i < 4; ++i)                                         \
                _Pragma("unroll")                                               \
                for (int j = 0; j < 4; ++j)                                     \
                    acc[i][j] = __builtin_amdgcn_mfma_f32_16x16x32_bf16(af[i], bfr[j], acc[i][j], 0, 0, 0); \
        }                                                                       \
        __syncthreads();                                                        \
    }

// K1: GEMM1 with TRANSPOSED epilogue: x written as (B, 3D, L) bf16.
__global__ __launch_bounds__(256) void k_gemm1_xt(
        const unsigned short* __restrict__ A, const unsigned short* __restrict__ Bw,
        const float* __restrict__ bias, unsigned short* __restrict__ xT,
        int K) {
    GEMM_CORE
    const int cq = lane >> 4;
    const int cn = lane & 15;
    const int b  = m0 >> 12;                         // m0 / LL (tile never spans b)
    const int lb = (m0 & 4095) + wr * 64 + cq * 4;   // l base for this lane
#pragma unroll
    for (int j = 0; j < 4; ++j) {
        int col = n0 + wc * 64 + j * 16 + cn;        // channel in [0, 3D)
        float bv = bias[col];
        unsigned short* cp = xT + ((size_t)b * TD + col) * LL + lb;
#pragma unroll
        for (int i = 0; i < 4; ++i) {
            uint2 p;
            p.x = cvt_pk_bf16(acc[i][j][0] + bv, acc[i][j][1] + bv);
            p.y = cvt_pk_bf16(acc[i][j][2] + bv, acc[i][j][3] + bv);
            *(uint2*)(cp + i * 16) = p;
        }
    }
}

// K6: GEMM2, fp32 row-major output (final result layout is fixed).
__global__ __launch_bounds__(256) void k_gemm_mfma(
        const unsigned short* __restrict__ A, const unsigned short* __restrict__ Bw,
        const float* __restrict__ bias, float* __restrict__ C,
        int N, int K) {
    GEMM_CORE
    const int cq = lane >> 4;
    const int cn = lane & 15;
#pragma unroll
    for (int j = 0; j < 4; ++j) {
        int col = n0 + wc * 64 + j * 16 + cn;
        float bv = bias[col];
#pragma unroll
        for (int i = 0; i < 4; ++i) {
            int rbase = m0 + wr * 64 + i * 16 + cq * 4;
#pragma unroll
            for (int r = 0; r < 4; ++r)
                C[(size_t)(rbase + r) * N + col] = acc[i][j][r] + bv;
        }
    }
}

// ---------------------------------------------------------------------------
// ld_row18: load x[l0-2 .. l0+15] (bf16) from a channel row into fp32 regs.
// ---------------------------------------------------------------------------
__device__ __forceinline__ void ld_row18(const unsigned short* __restrict__ r,
                                         int l0, float* a) {
    unsigned ql = 0;
    if (l0 >= 2) ql = *(const unsigned*)(r + l0 - 2);
    a[0] = b2f((unsigned short)(ql & 0xffffu));
    a[1] = b2f((unsigned short)(ql >> 16));
    uint4 q0 = *(const uint4*)(r + l0);
    uint4 q1 = *(const uint4*)(r + l0 + 8);
    unsigned qq[8] = {q0.x, q0.y, q0.z, q0.w, q1.x, q1.y, q1.z, q1.w};
#pragma unroll
    for (int k2 = 0; k2 < 8; ++k2) {
        a[2 + 2 * k2] = b2f((unsigned short)(qq[k2] & 0xffffu));
        a[3 + 2 * k2] = b2f((unsigned short)(qq[k2] >> 16));
    }
}

// ---------------------------------------------------------------------------
// K2+K4 FUSED v2: depthwise short conv (k=3, causal) + pre-gate +
// register-FFT long conv + post-gate. ONE BATCH-PAIR PER BLOCK (grid 1536,
// like the proven fftconv3 — restores occupancy). kf is STREAMED in the
// pointwise loop (no w[32] register hold -> no spills). Staging uses an
// XOR swizzle SW(l)=l^((l>>4)&15): writer (l=16t+k) gets bank k^(t&15)
// (conflict-free b64); reader (l=t+256j) gets (t&15)^(t>>4) (conflict-free).
// ---------------------------------------------------------------------------
#define SW(l) ((l) ^ (((l) >> 4) & 15))

__global__ __launch_bounds__(256) void k_convfft(
        const unsigned short* __restrict__ xT,
        const float* __restrict__ conv_w, const float* __restrict__ conv_b,
        const float2* __restrict__ kf,
        unsigned short* __restrict__ yg) {
    __shared__ float2 buf[FFT_LDS];
    const int bp = blockIdx.x;
    const int d = bp % DD;
    const int pair = bp / DD;
    const int b0 = pair * 2, b1 = b0 + 1;
    const int t = threadIdx.x;
    const int l0 = t << 4;
    const float w10 = conv_w[3*d],          w11 = conv_w[3*d+1],          w12 = conv_w[3*d+2];
    const float w20 = conv_w[3*(DD+d)],     w21 = conv_w[3*(DD+d)+1],     w22 = conv_w[3*(DD+d)+2];
    const float w30 = conv_w[3*(2*DD+d)],   w31 = conv_w[3*(2*DD+d)+1],   w32 = conv_w[3*(2*DD+d)+2];
    const float c1 = conv_b[d], c2 = conv_b[DD + d], c3 = conv_b[2*DD + d];
    float2*   vstage = buf;                        // [4096] float2 (v pairs, fp32)
    unsigned* xstage = (unsigned*)(buf + 4096);    // [4096] packed bf16 x2 pairs

    // --- conv compute + swizzled stage ---
    {
        float a[18], q1[16], vv[16];
        ld_row18(xT + ((size_t)b0 * TD + d) * LL, l0, a);
#pragma unroll
        for (int k = 0; k < 16; ++k) q1[k] = w10*a[k] + w11*a[k+1] + w12*a[k+2] + c1;
        ld_row18(xT + ((size_t)b0 * TD + 2*DD + d) * LL, l0, a);
#pragma unroll
        for (int k = 0; k < 16; ++k) vv[k] = (w30*a[k] + w31*a[k+1] + w32*a[k+2] + c3) * q1[k];
        ld_row18(xT + ((size_t)b1 * TD + d) * LL, l0, a);
#pragma unroll
        for (int k = 0; k < 16; ++k) q1[k] = w10*a[k] + w11*a[k+1] + w12*a[k+2] + c1;
        ld_row18(xT + ((size_t)b1 * TD + 2*DD + d) * LL, l0, a);
#pragma unroll
        for (int k = 0; k < 16; ++k)
            vstage[SW(l0 + k)] = make_float2(vv[k], (w30*a[k] + w31*a[k+1] + w32*a[k+2] + c3) * q1[k]);
        ld_row18(xT + ((size_t)b0 * TD + DD + d) * LL, l0, a);
#pragma unroll
        for (int k = 0; k < 16; ++k) q1[k] = w20*a[k] + w21*a[k+1] + w22*a[k+2] + c2;
        ld_row18(xT + ((size_t)b1 * TD + DD + d) * LL, l0, a);
#pragma unroll
        for (int k = 0; k < 16; ++k)
            xstage[SW(l0 + k)] = cvt_pk_bf16(q1[k], w20*a[k] + w21*a[k+1] + w22*a[k+2] + c2);
    }
    __syncthreads();
    // --- redistribute to strided FFT ownership (swizzled read, conflict-free) ---
    float2 R[32];
    unsigned x2p[16];
#pragma unroll
    for (int j = 0; j < 16; ++j) {
        int idx = t + 256 * j;
        R[j] = vstage[SW(idx)];
        x2p[j] = xstage[SW(idx)];
        R[16 + j] = make_float2(0.f, 0.f);
    }
    // (eng_fwd's internal pre-write __syncthreads protects the reads above)
    eng_fwd(buf, R, t);
    const float2* kd = kf + (size_t)d * NFFT;
#pragma unroll
    for (int i = 0; i < 32; ++i) {
        float2 w = kd[i * 256 + t];          // streamed — no register hold
        float2 zv = R[i];
        R[i] = make_float2(zv.x * w.x - zv.y * w.y, zv.x * w.y + zv.y * w.x);
    }
    eng_inv(buf, R, t);
    unsigned short* o1 = yg + ((size_t)b0 * DD + d) * LL;
    unsigned short* o2 = o1 + (size_t)DD * LL;
#pragma unroll
    for (int j = 0; j < 16; ++j) {
        int idx = t + 256 * j;
        o1[idx] = f2b(R[j].x * b2f((unsigned short)(x2p[j] & 0xffffu)));
        o2[idx] = f2b(R[j].y * b2f((unsigned short)(x2p[j] >> 16)));
    }
}

// ---------------------------------------------------------------------------
// K3a: implicit filter MLP; output TRANSPOSED h3g[16][LL]
// ---------------------------------------------------------------------------
__global__ __launch_bounds__(256) void k_filter_mlp(
        const float* __restrict__ z,
        const float* __restrict__ fw1, const float* __restrict__ fb1,
        const float* __restrict__ fw2, const float* __restrict__ fb2,
        const float* __restrict__ fw3, const float* __restrict__ fb3,
        const float* __restrict__ freq, float* __restrict__ h3g) {
    int l = blockIdx.x * 256 + threadIdx.x;
    float z0 = z[l*3+0], z1 = z[l*3+1], z2 = z[l*3+2];
    float h1[16], h2[16];
#pragma unroll
    for (int j = 0; j < 16; ++j) {
        float a = z0*fw1[j*3+0] + z1*fw1[j*3+1] + z2*fw1[j*3+2] + fb1[j];
        h1[j] = sinf(freq[j] * a);
    }
#pragma unroll
    for (int j = 0; j < 16; ++j) {
        float a = fb2[j];
#pragma unroll
        for (int i = 0; i < 16; ++i) a += h1[i] * fw2[j*16+i];
        h2[j] = sinf(freq[j] * a);
    }
#pragma unroll
    for (int j = 0; j < 16; ++j) {
        float a = fb3[j];
#pragma unroll
        for (int i = 0; i < 16; ++i) a += h2[i] * fw3[j*16+i];
        h3g[j * LL + l] = sinf(freq[j] * a);
    }
}

// ---------------------------------------------------------------------------
// K3b: fused filter construction + forward FFT; kf in engine order, 1/N and
// filter_bias folded in.
// ---------------------------------------------------------------------------
__global__ __launch_bounds__(256) void k_filter_fft(
        const float* __restrict__ h3g, const float* __restrict__ fw4,
        const float* __restrict__ fbias, float2* __restrict__ kf) {
    __shared__ float2 buf[FFT_LDS];
    const int d = blockIdx.x, t = threadIdx.x;
    float w4[16];
#pragma unroll
    for (int i = 0; i < 16; ++i) w4[i] = fw4[d * 16 + i];
    const float min_d = 3.070113457325394f;
    const float max_d = 15.35056728662697f;
    const float ad = min_d + (max_d - min_d) * ((float)d / 767.0f);
    float2 R[32];
#pragma unroll
    for (int j = 0; j < 16; ++j) {
        int l = t + 256 * j;
        float acc = 0.f;
#pragma unroll
        for (int i = 0; i < 16; ++i) acc += h3g[i * LL + l] * w4[i];
        acc *= __expf(-((float)l / 4095.0f) * ad);
        R[j] = make_float2(acc, 0.f);
        R[16 + j] = make_float2(0.f, 0.f);
    }
    eng_fwd(buf, R, t);
    const float fb = fbias[d];
    const float inv_n = 1.0f / (float)NFFT;
    float2* kd = kf + (size_t)d * NFFT;
#pragma unroll
    for (int i = 0; i < 32; ++i)
        kd[i * 256 + t] = make_float2((R[i].x + fb) * inv_n, R[i].y * inv_n);
}

// ---------------------------------------------------------------------------
// K5: transpose: yg (B,D,L) bf16 -> ygT (B,L,D) bf16, 64x64 LDS tile
// ---------------------------------------------------------------------------
__global__ __launch_bounds__(256) void k_transpose_cast(
        const unsigned short* __restrict__ yg, unsigned short* __restrict__ ygT) {
    __shared__ float t[64][65];
    const int b = blockIdx.z;
    const int d0 = blockIdx.y * 64;
    const int l0 = blockIdx.x * 64;
    for (int idx = threadIdx.x; idx < 4096; idx += 256) {
        int r = idx >> 6, c = idx & 63;
        t[r][c] = b2f(yg[((size_t)(b * DD + d0 + r)) * LL + l0 + c]);
    }
    __syncthreads();
    for (int idx = threadIdx.x; idx < 2048; idx += 256) {
        int r = idx >> 5, c = (idx & 31) * 2;
        unsigned int p = (unsigned int)f2b(t[c][r]) | ((unsigned int)f2b(t[c+1][r]) << 16);
        *(unsigned int*)&ygT[((size_t)(b * LL + l0 + r)) * DD + d0 + c] = p;
    }
}

// ---------------------------------------------------------------------------
extern "C" void kernel_launch(void* const* d_in, const int* in_sizes, int n_in,
                              void* d_out, int out_size, void* d_ws, size_t ws_size,
                              hipStream_t stream) {
    const float* u      = (const float*)d_in[0];
    const float* w_in   = (const float*)d_in[1];
    const float* b_in   = (const float*)d_in[2];
    const float* w_out  = (const float*)d_in[3];
    const float* b_out  = (const float*)d_in[4];
    const float* conv_w = (const float*)d_in[5];
    const float* conv_b = (const float*)d_in[6];
    const float* z      = (const float*)d_in[7];
    const float* fw1    = (const float*)d_in[8];
    const float* fb1    = (const float*)d_in[9];
    const float* fw2    = (const float*)d_in[10];
    const float* fb2    = (const float*)d_in[11];
    const float* fw3    = (const float*)d_in[12];
    const float* fb3    = (const float*)d_in[13];
    const float* fw4    = (const float*)d_in[14];
    const float* freq   = (const float*)d_in[15];
    const float* fbias  = (const float*)d_in[16];

    // Workspace layout (xT and kf COEXIST — no aliasing):
    //   xT       @ 0          75,497,472  (B,3D,L bf16)
    //   kf       @ 75497472   50,331,648  (D x NFFT float2)
    //   h3g      @ 125829120     262,144
    //   w_out_bf @ 126091264   1,179,648
    //   yg       @ 127270912  25,165,824  (B,D,L bf16, gated y)
    //   ygT      @ 152436736  25,165,824
    //   u_bf     @ 177602560  25,165,824
    //   w_in_bf  @ 202768384   3,538,944   -> high water ~206.3 MB
    char* ws = (char*)d_ws;
    unsigned short* xT       = (unsigned short*)(ws);
    float2* kf               = (float2*)(ws + 75497472);
    float*  h3g              = (float*)(ws + 125829120);
    unsigned short* w_out_bf = (unsigned short*)(ws + 126091264);
    unsigned short* yg       = (unsigned short*)(ws + 127270912);
    unsigned short* ygT      = (unsigned short*)(ws + 152436736);
    unsigned short* u_bf     = (unsigned short*)(ws + 177602560);
    unsigned short* w_in_bf  = (unsigned short*)(ws + 202768384);

    // 0) cast u, w_in to bf16
    k_cast_pair<<<(3145728 + 442368 + 255) / 256, 256, 0, stream>>>(
        u, 3145728ULL, w_in, 442368ULL, u_bf, w_in_bf);
    // 1) x = u @ w_in^T + b_in  (bf16 MFMA), written TRANSPOSED as (B,3D,L)
    k_gemm1_xt<<<dim3(TD/128, (BB*LL)/128), 256, 0, stream>>>(u_bf, w_in_bf, b_in, xT, DD);
    // 2) filter: MLP -> fused (modulated k + FFT), engine-order spectrum
    k_filter_mlp<<<LL/256, 256, 0, stream>>>(z, fw1, fb1, fw2, fb2, fw3, fb3, freq, h3g);
    k_filter_fft<<<DD, 256, 0, stream>>>(h3g, fw4, fbias, kf);
    // 2b) cast w_out -> bf16
    k_cast_pair<<<(147456 + 255) / 256, 256, 0, stream>>>(
        w_out, 147456ULL, (const float*)0, 0ULL, w_out_bf, (unsigned short*)0);
    // 3) FUSED short conv + pre-gate + FFT long conv + post-gate (grid 1536)
    k_convfft<<<(BB/2)*DD, 256, 0, stream>>>(xT, conv_w, conv_b, kf, yg);
    // 4) transpose gated y -> (B,L,D) bf16
    k_transpose_cast<<<dim3(LL/64, DD/64, BB), 256, 0, stream>>>(yg, ygT);
    // 5) out = ygT @ w_out^T + b_out  (bf16 MFMA, fp32 out)
    k_gemm_mfma<<<dim3(DD/128, (BB*LL)/128), 256, 0, stream>>>(ygT, w_out_bf, b_out, (float*)d_out, DD, DD);
}